// Round 1
// baseline (142.950 us; speedup 1.0000x reference)
//
#include <hip/hip_runtime.h>

// Chamfer loss between subsampled point clouds.
// srcA: (64000,2) fp32 -> A = 8000 pts (linspace stride ~8.0009, fp32 trunc)
// srcB: (80000,2) fp32 -> B = 10000 pts (linspace stride ~8.0008, fp32 trunc)
// out  = 0.5 * ( mean_i min_j |A_i - B_j|  +  mean_j min_i |A_i - B_j| )

#define SRC_A 64000
#define SRC_B 80000
#define NA 8000
#define NB 10000
#define CHUNK 2000   // column points staged in LDS per block (16 KB)

// ---- workspace layout (bytes) ----
// A     : float2[NA]   @ 0        (64000 B)
// B     : float2[NB]   @ 64000    (80000 B)
// minA  : uint  [NA]   @ 144000   (32000 B)
// minB  : uint  [NB]   @ 176000   (40000 B)   total 216000 B

__global__ void gather_init(const float* __restrict__ srcA,
                            const float* __restrict__ srcB,
                            float2* __restrict__ A, float2* __restrict__ B,
                            unsigned* __restrict__ minA, unsigned* __restrict__ minB) {
    int t = blockIdx.x * blockDim.x + threadIdx.x;
    if (t < NA) {
        // jnp.linspace(0, 63999, 8000) in fp32, truncate to int32
        float delta = (float)(SRC_A - 1) / (float)(NA - 1);
        int idx = (int)((float)t * delta);
        if (idx > SRC_A - 1) idx = SRC_A - 1;
        A[t] = make_float2(srcA[2 * idx], srcA[2 * idx + 1]);
        minA[t] = 0x7f800000u;  // +inf
    }
    if (t < NB) {
        float delta = (float)(SRC_B - 1) / (float)(NB - 1);
        int idx = (int)((float)t * delta);
        if (idx > SRC_B - 1) idx = SRC_B - 1;
        B[t] = make_float2(srcB[2 * idx], srcB[2 * idx + 1]);
        minB[t] = 0x7f800000u;
    }
}

// Each thread owns one row point; block stages a CHUNK of column points in LDS.
// All lanes read the same LDS word per iteration -> broadcast (conflict-free).
// Track min of SQUARED distance (sqrt is monotone; applied once in the reduce).
__global__ __launch_bounds__(256) void rowmin(const float2* __restrict__ rows, int nrows,
                                              const float2* __restrict__ cols, int ncols,
                                              unsigned* __restrict__ outmin) {
    __shared__ float2 sc[CHUNK];
    int c0 = blockIdx.y * CHUNK;
    int cn = ncols - c0; if (cn > CHUNK) cn = CHUNK;
    for (int j = (int)threadIdx.x; j < cn; j += (int)blockDim.x)
        sc[j] = cols[c0 + j];
    __syncthreads();

    int r = blockIdx.x * blockDim.x + threadIdx.x;
    if (r >= nrows) return;
    float2 p = rows[r];
    float m = __builtin_inff();
    int j = 0;
    for (; j + 8 <= cn; j += 8) {
#pragma unroll
        for (int u = 0; u < 8; ++u) {
            float2 q = sc[j + u];
            float dx = p.x - q.x;
            float dy = p.y - q.y;
            float d = fmaf(dx, dx, dy * dy);
            m = fminf(m, d);
        }
    }
    for (; j < cn; ++j) {
        float2 q = sc[j];
        float dx = p.x - q.x;
        float dy = p.y - q.y;
        float d = fmaf(dx, dx, dy * dy);
        m = fminf(m, d);
    }
    // squared distances are non-negative -> float bits are order-monotone as uint
    atomicMin(outmin + r, __float_as_uint(m));
}

__global__ __launch_bounds__(1024) void reduce_out(const unsigned* __restrict__ minA,
                                                   const unsigned* __restrict__ minB,
                                                   float* __restrict__ out) {
    float s = 0.0f;
    for (int i = (int)threadIdx.x; i < NA; i += 1024)
        s += sqrtf(__uint_as_float(minA[i])) * (0.5f / (float)NA);
    for (int i = (int)threadIdx.x; i < NB; i += 1024)
        s += sqrtf(__uint_as_float(minB[i])) * (0.5f / (float)NB);

    // block reduction: wave shuffle then LDS
    for (int off = 32; off > 0; off >>= 1) s += __shfl_down(s, off, 64);
    __shared__ float red[16];
    int wave = (int)threadIdx.x >> 6;
    if ((threadIdx.x & 63) == 0) red[wave] = s;
    __syncthreads();
    if (threadIdx.x == 0) {
        float t = 0.0f;
#pragma unroll
        for (int w = 0; w < 16; ++w) t += red[w];
        *out = t;
    }
}

extern "C" void kernel_launch(void* const* d_in, const int* in_sizes, int n_in,
                              void* d_out, int out_size, void* d_ws, size_t ws_size,
                              hipStream_t stream) {
    const float* srcA = (const float*)d_in[0];  // img_render_points (1000*64*2)
    const float* srcB = (const float*)d_in[1];  // ref point cloud (80000*2)
    char* ws = (char*)d_ws;
    float2*   A    = (float2*)(ws + 0);
    float2*   B    = (float2*)(ws + 64000);
    unsigned* minA = (unsigned*)(ws + 144000);
    unsigned* minB = (unsigned*)(ws + 176000);
    float* out = (float*)d_out;

    gather_init<<<(NB + 255) / 256, 256, 0, stream>>>(srcA, srcB, A, B, minA, minB);

    dim3 g1((NA + 255) / 256, (NB + CHUNK - 1) / CHUNK);
    rowmin<<<g1, 256, 0, stream>>>(A, NA, B, NB, minA);

    dim3 g2((NB + 255) / 256, (NA + CHUNK - 1) / CHUNK);
    rowmin<<<g2, 256, 0, stream>>>(B, NB, A, NA, minB);

    reduce_out<<<1, 1024, 0, stream>>>(minA, minB, out);
}

// Round 2
// 87.172 us; speedup vs baseline: 1.6399x; 1.6399x over previous
//
#include <hip/hip_runtime.h>

// Chamfer loss between subsampled point clouds.
// srcA: (64000,2) fp32 -> A = 8000 pts  (fp32 linspace trunc)
// srcB: (80000,2) fp32 -> B = 10000 pts
// out  = 0.5 * ( mean_i min_j |A_i - B_j| + mean_j min_i |A_i - B_j| )
//
// Two generic row-min passes over SQUARED distances (sqrt is monotone,
// applied once at the end). Each block: 256 threads, 2 rows/thread,
// stages 256 column points in LDS (broadcast reads, conflict-free),
// commits running min via atomicMin on the uint bit pattern (valid for
// non-negative floats). Min arrays pre-set to 0xFFFFFFFF via memsetAsync.

#define SRC_A 64000
#define SRC_B 80000
#define NA 8000
#define NB 10000
#define CHUNK 256      // columns staged in LDS per block
#define ROWS_PER_T 2   // rows per thread
#define BLOCK 256

// ---- workspace layout (bytes) ----
// minA : uint[NA] @ 0      (32000 B)
// minB : uint[NB] @ 32000  (40000 B)   total 72000 B

__global__ __launch_bounds__(BLOCK) void rowmin_fused(
        const float* __restrict__ srcRows, float rowDelta, int rowSrcMax, int nrows,
        const float* __restrict__ srcCols, float colDelta, int colSrcMax, int ncols,
        unsigned* __restrict__ outmin) {
    __shared__ float2 sc[CHUNK];
    int c0 = blockIdx.y * CHUNK;
    int cn = ncols - c0; if (cn > CHUNK) cn = CHUNK;

    // gather this block's column chunk (linspace subsample) into LDS
    int j = (int)threadIdx.x;
    if (j < cn) {
        int cidx = (int)((float)(c0 + j) * colDelta);
        if (cidx > colSrcMax) cidx = colSrcMax;
        sc[j] = make_float2(srcCols[2 * cidx], srcCols[2 * cidx + 1]);
    }
    __syncthreads();

    // two rows per thread (coalesced-ish: r1 = r0 + BLOCK)
    int r0 = blockIdx.x * (BLOCK * ROWS_PER_T) + (int)threadIdx.x;
    int r1 = r0 + BLOCK;
    int l0 = r0 < nrows ? r0 : nrows - 1;   // clamp for load; guard the atomic
    int l1 = r1 < nrows ? r1 : nrows - 1;
    int i0 = (int)((float)l0 * rowDelta); if (i0 > rowSrcMax) i0 = rowSrcMax;
    int i1 = (int)((float)l1 * rowDelta); if (i1 > rowSrcMax) i1 = rowSrcMax;
    float2 p0 = make_float2(srcRows[2 * i0], srcRows[2 * i0 + 1]);
    float2 p1 = make_float2(srcRows[2 * i1], srcRows[2 * i1 + 1]);

    float m0a = __builtin_inff(), m0b = __builtin_inff();
    float m1a = __builtin_inff(), m1b = __builtin_inff();

    int k = 0;
    for (; k + 4 <= cn; k += 4) {
        float2 q0 = sc[k + 0];
        float2 q1 = sc[k + 1];
        float2 q2 = sc[k + 2];
        float2 q3 = sc[k + 3];
        float dx, dy;
        dx = p0.x - q0.x; dy = p0.y - q0.y; m0a = fminf(m0a, fmaf(dx, dx, dy * dy));
        dx = p0.x - q1.x; dy = p0.y - q1.y; m0b = fminf(m0b, fmaf(dx, dx, dy * dy));
        dx = p0.x - q2.x; dy = p0.y - q2.y; m0a = fminf(m0a, fmaf(dx, dx, dy * dy));
        dx = p0.x - q3.x; dy = p0.y - q3.y; m0b = fminf(m0b, fmaf(dx, dx, dy * dy));
        dx = p1.x - q0.x; dy = p1.y - q0.y; m1a = fminf(m1a, fmaf(dx, dx, dy * dy));
        dx = p1.x - q1.x; dy = p1.y - q1.y; m1b = fminf(m1b, fmaf(dx, dx, dy * dy));
        dx = p1.x - q2.x; dy = p1.y - q2.y; m1a = fminf(m1a, fmaf(dx, dx, dy * dy));
        dx = p1.x - q3.x; dy = p1.y - q3.y; m1b = fminf(m1b, fmaf(dx, dx, dy * dy));
    }
    for (; k < cn; ++k) {
        float2 q = sc[k];
        float dx0 = p0.x - q.x, dy0 = p0.y - q.y;
        m0a = fminf(m0a, fmaf(dx0, dx0, dy0 * dy0));
        float dx1 = p1.x - q.x, dy1 = p1.y - q.y;
        m1a = fminf(m1a, fmaf(dx1, dx1, dy1 * dy1));
    }

    float m0 = fminf(m0a, m0b);
    float m1 = fminf(m1a, m1b);
    if (r0 < nrows) atomicMin(outmin + r0, __float_as_uint(m0));
    if (r1 < nrows) atomicMin(outmin + r1, __float_as_uint(m1));
}

__global__ __launch_bounds__(1024) void reduce_out(const unsigned* __restrict__ minA,
                                                   const unsigned* __restrict__ minB,
                                                   float* __restrict__ out) {
    float s = 0.0f;
    for (int i = (int)threadIdx.x; i < NA; i += 1024)
        s += sqrtf(__uint_as_float(minA[i])) * (0.5f / (float)NA);
    for (int i = (int)threadIdx.x; i < NB; i += 1024)
        s += sqrtf(__uint_as_float(minB[i])) * (0.5f / (float)NB);

    for (int off = 32; off > 0; off >>= 1) s += __shfl_down(s, off, 64);
    __shared__ float red[16];
    int wave = (int)threadIdx.x >> 6;
    if ((threadIdx.x & 63) == 0) red[wave] = s;
    __syncthreads();
    if (threadIdx.x == 0) {
        float t = 0.0f;
#pragma unroll
        for (int w = 0; w < 16; ++w) t += red[w];
        *out = t;
    }
}

extern "C" void kernel_launch(void* const* d_in, const int* in_sizes, int n_in,
                              void* d_out, int out_size, void* d_ws, size_t ws_size,
                              hipStream_t stream) {
    const float* srcA = (const float*)d_in[0];  // img_render_points (1000*64*2)
    const float* srcB = (const float*)d_in[1];  // ref point cloud (80000*2)
    char* ws = (char*)d_ws;
    unsigned* minA = (unsigned*)(ws + 0);
    unsigned* minB = (unsigned*)(ws + 32000);
    float* out = (float*)d_out;

    // 0xFFFFFFFF = uint max -> valid init for atomicMin
    hipMemsetAsync(ws, 0xFF, 72000, stream);

    const float dA = (float)(SRC_A - 1) / (float)(NA - 1);
    const float dB = (float)(SRC_B - 1) / (float)(NB - 1);

    // pass 1: rows = A (8000), cols = B (10000)
    dim3 g1((NA + BLOCK * ROWS_PER_T - 1) / (BLOCK * ROWS_PER_T),
            (NB + CHUNK - 1) / CHUNK);
    rowmin_fused<<<g1, BLOCK, 0, stream>>>(srcA, dA, SRC_A - 1, NA,
                                           srcB, dB, SRC_B - 1, NB, minA);

    // pass 2: rows = B (10000), cols = A (8000)
    dim3 g2((NB + BLOCK * ROWS_PER_T - 1) / (BLOCK * ROWS_PER_T),
            (NA + CHUNK - 1) / CHUNK);
    rowmin_fused<<<g2, BLOCK, 0, stream>>>(srcB, dB, SRC_B - 1, NB,
                                           srcA, dA, SRC_A - 1, NA, minB);

    reduce_out<<<1, 1024, 0, stream>>>(minA, minB, out);
}

// Round 3
// 84.515 us; speedup vs baseline: 1.6914x; 1.0314x over previous
//
#include <hip/hip_runtime.h>

// Chamfer loss between subsampled point clouds (exact-form distances).
// srcA: (64000,2) fp32 -> A = 8000 pts  (fp32 linspace trunc, matches jnp)
// srcB: (80000,2) fp32 -> B = 10000 pts
// out  = 0.5 * ( mean_i min_j |A_i - B_j| + mean_j min_i |A_i - B_j| )
//
// Two dispatches only:
//  1) chamfer_partial: flat grid covering BOTH directions. Each block owns
//     (row-group of 1024, column-chunk of 256). Columns staged in LDS
//     (broadcast reads -> conflict-free). 4 rows/thread = 4 independent
//     fmin chains; one LDS read feeds 20 VALU ops (DS pipe fully hidden).
//     Partial min of SQUARED distance direct-stored per (row, chunk) -> no
//     atomics, no init needed. Block 0 zeroes d_out for the reduce.
//  2) reduce_out: min over chunks per row, sqrt, scaled sum, per-block
//     atomicAdd into d_out (sqrt is monotone so applied after the min).

#define SRC_A 64000
#define SRC_B 80000
#define NA 8000
#define NB 10000

#define BLOCK 256
#define CHUNK 256          // columns staged in LDS per block
#define RPT 4              // rows per thread
#define RPB (BLOCK * RPT)  // 1024 rows per block

#define NB1X 8    // ceil(8000/1024)   row-groups, pass 1
#define NB1Y 40   // ceil(10000/256)   col-chunks, pass 1
#define NB2X 10   // ceil(10000/1024)  row-groups, pass 2
#define NB2Y 32   // ceil(8000/256)    col-chunks, pass 2
#define NBLK1 (NB1X * NB1Y)           // 320
#define NBLK2 (NB2X * NB2Y)           // 320

#define P1_STRIDE (NB1X * RPB)        // 8192 (padded row count, pass 1)
#define P2_STRIDE (NB2X * RPB)        // 10240
// ws layout: P1 float[NB1Y * P1_STRIDE] @ 0 (1310720 B);
//            P2 float[NB2Y * P2_STRIDE] @ 1310720 (1310720 B)
#define P2_OFF 1310720

__global__ __launch_bounds__(BLOCK) void chamfer_partial(
        const float2* __restrict__ srcA, const float2* __restrict__ srcB,
        float* __restrict__ ws, float* __restrict__ out) {
    if (blockIdx.x == 0 && threadIdx.x == 0) *out = 0.0f;  // init for reduce's atomicAdd

    const bool pass1 = (int)blockIdx.x < NBLK1;
    const float2* srcRows; const float2* srcCols;
    float rowDelta, colDelta;
    int rowSrcMax, colSrcMax, nrows, ncols, bx, by, pstride;
    float* P;
    if (pass1) {
        int f = (int)blockIdx.x;
        bx = f % NB1X; by = f / NB1X;
        srcRows = srcA; rowDelta = (float)(SRC_A - 1) / (float)(NA - 1);
        rowSrcMax = SRC_A - 1; nrows = NA;
        srcCols = srcB; colDelta = (float)(SRC_B - 1) / (float)(NB - 1);
        colSrcMax = SRC_B - 1; ncols = NB;
        P = ws; pstride = P1_STRIDE;
    } else {
        int f = (int)blockIdx.x - NBLK1;
        bx = f % NB2X; by = f / NB2X;
        srcRows = srcB; rowDelta = (float)(SRC_B - 1) / (float)(NB - 1);
        rowSrcMax = SRC_B - 1; nrows = NB;
        srcCols = srcA; colDelta = (float)(SRC_A - 1) / (float)(NA - 1);
        colSrcMax = SRC_A - 1; ncols = NA;
        P = ws + (P2_OFF / 4); pstride = P2_STRIDE;
    }

    __shared__ float2 sc[CHUNK];
    int c0 = by * CHUNK;
    int cn = ncols - c0; if (cn > CHUNK) cn = CHUNK;
    int j = (int)threadIdx.x;
    if (j < cn) {
        int cidx = (int)((float)(c0 + j) * colDelta);
        if (cidx > colSrcMax) cidx = colSrcMax;
        sc[j] = srcCols[cidx];
    }
    __syncthreads();

    // 4 rows per thread: r_i = bx*1024 + i*256 + tid  (coalesced stores)
    float2 p[RPT];
    float  m[RPT];
    int r0 = bx * RPB + (int)threadIdx.x;
#pragma unroll
    for (int i = 0; i < RPT; ++i) {
        int r = r0 + i * BLOCK;
        int l = r < nrows ? r : nrows - 1;               // clamp for load; guard store
        int ridx = (int)((float)l * rowDelta);
        if (ridx > rowSrcMax) ridx = rowSrcMax;
        p[i] = srcRows[ridx];
        m[i] = __builtin_inff();
    }

    int k = 0;
    for (; k + 2 <= cn; k += 2) {
        float2 q0 = sc[k];
        float2 q1 = sc[k + 1];
#pragma unroll
        for (int i = 0; i < RPT; ++i) {
            float dx = p[i].x - q0.x, dy = p[i].y - q0.y;
            m[i] = fminf(m[i], fmaf(dx, dx, dy * dy));
            dx = p[i].x - q1.x; dy = p[i].y - q1.y;
            m[i] = fminf(m[i], fmaf(dx, dx, dy * dy));
        }
    }
    if (k < cn) {
        float2 q = sc[k];
#pragma unroll
        for (int i = 0; i < RPT; ++i) {
            float dx = p[i].x - q.x, dy = p[i].y - q.y;
            m[i] = fminf(m[i], fmaf(dx, dx, dy * dy));
        }
    }

#pragma unroll
    for (int i = 0; i < RPT; ++i) {
        int r = r0 + i * BLOCK;
        if (r < nrows) P[by * pstride + r] = m[i];
    }
}

__global__ __launch_bounds__(BLOCK) void reduce_out(const float* __restrict__ ws,
                                                    float* __restrict__ out) {
    const float* P1 = ws;
    const float* P2 = ws + (P2_OFF / 4);
    float s = 0.0f;
    for (int t = (int)(blockIdx.x * BLOCK + threadIdx.x); t < NA + NB;
         t += (int)(gridDim.x * BLOCK)) {
        float mn = __builtin_inff();
        if (t < NA) {
#pragma unroll
            for (int c = 0; c < NB1Y; ++c) mn = fminf(mn, P1[c * P1_STRIDE + t]);
            s += sqrtf(mn) * (0.5f / (float)NA);
        } else {
            int r = t - NA;
#pragma unroll
            for (int c = 0; c < NB2Y; ++c) mn = fminf(mn, P2[c * P2_STRIDE + r]);
            s += sqrtf(mn) * (0.5f / (float)NB);
        }
    }
    // wave shuffle reduce, then LDS across the 4 waves, then one atomicAdd
    for (int off = 32; off > 0; off >>= 1) s += __shfl_down(s, off, 64);
    __shared__ float red[4];
    int wave = (int)threadIdx.x >> 6;
    if ((threadIdx.x & 63) == 0) red[wave] = s;
    __syncthreads();
    if (threadIdx.x == 0) {
        float t = red[0] + red[1] + red[2] + red[3];
        atomicAdd(out, t);
    }
}

extern "C" void kernel_launch(void* const* d_in, const int* in_sizes, int n_in,
                              void* d_out, int out_size, void* d_ws, size_t ws_size,
                              hipStream_t stream) {
    (void)in_sizes; (void)n_in; (void)out_size; (void)ws_size;
    const float2* srcA = (const float2*)d_in[0];  // img_render_points (1000*64*2)
    const float2* srcB = (const float2*)d_in[1];  // ref point cloud (80000*2)
    float* ws = (float*)d_ws;
    float* out = (float*)d_out;

    chamfer_partial<<<NBLK1 + NBLK2, BLOCK, 0, stream>>>(srcA, srcB, ws, out);
    reduce_out<<<64, BLOCK, 0, stream>>>(ws, out);
}